// Round 17
// baseline (8366.236 us; speedup 1.0000x reference)
//
#include <hip/hip_runtime.h>
#include <stdint.h>

#define B_ 16
#define T_ 2048
#define I_ 512
#define H_ 512
#define G4 2048
#define NW 64          // workgroups in the persistent kernel
#define JJ 8           // h-columns owned per WG (H_/NW)

// bf16 NaN sentinel: |h| < 1 always (h = sigm*tanh), h0 is finite normal data,
// so 0x7FC0 can never occur in live h data.
#define SENT64 0x7FC07FC07FC07FC0ULL

typedef __bf16 bf16x8 __attribute__((ext_vector_type(8)));
typedef __bf16 bf16x4 __attribute__((ext_vector_type(4)));
typedef float  f32x4  __attribute__((ext_vector_type(4)));

__device__ __forceinline__ float sigm(float x) {
    return __builtin_amdgcn_rcpf(1.f + __builtin_amdgcn_exp2f(-1.44269504f * x));
}
__device__ __forceinline__ float tanh_f(float x) {
    float xc = fmaxf(x, -40.f);                       // avoid inf*0 = NaN
    float e  = __builtin_amdgcn_exp2f(-2.88539008f * xc);
    return (1.f - e) * __builtin_amdgcn_rcpf(1.f + e);
}

// ---- prep: x [B][T][I] fp32 -> xp [T][B][I] bf16 ----
__global__ void pack_x(const float* __restrict__ x, __bf16* __restrict__ xp) {
    int q = blockIdx.x * 256 + threadIdx.x;   // 4 elems each
    int o = q * 4;                            // dst linear over [T][B][I]
    int i  = o & (I_ - 1);
    int tb = o >> 9;
    int b  = tb & (B_ - 1);
    int t  = tb >> 4;
    float4 v = *(const float4*)(x + ((size_t)(b * T_ + t) * I_ + i));
    *(bf16x4*)(xp + o) = (bf16x4){(__bf16)v.x, (__bf16)v.y, (__bf16)v.z, (__bf16)v.w};
}

// ---- prep: pack Wi/Wh rows per-WG: wp[w][n][k], n = gate*8 + jj, row = gate*512 + w*8 + jj
__global__ void pack_w(const float* __restrict__ Wi, const float* __restrict__ Wh,
                       __bf16* __restrict__ wip, __bf16* __restrict__ whp) {
    int q = blockIdx.x * 256 + threadIdx.x;   // total 2*64*32*128 threads, 4 k each
    int k = (q & 127) * 4;  q >>= 7;
    int n = q & 31;         q >>= 5;
    int w = q & 63;         q >>= 6;
    int mat = q;
    int row = (n >> 3) * 512 + w * JJ + (n & 7);
    const float* src = (mat ? Wh : Wi) + (size_t)row * 512 + k;
    float4 v = *(const float4*)src;
    __bf16* dst = (mat ? whp : wip) + ((size_t)(w * 32 + n) * 512 + k);
    *(bf16x4*)dst = (bf16x4){(__bf16)v.x, (__bf16)v.y, (__bf16)v.z, (__bf16)v.w};
}

// ---- prep: h0 -> hbuf[0] (bf16), poison hbuf[1],hbuf[2], bias pack ----
__global__ void prep_small(const float* __restrict__ h0, const float* __restrict__ bi,
                           const float* __restrict__ bh, __bf16* __restrict__ hbuf,
                           float* __restrict__ biasp) {
    int i = blockIdx.x * 256 + threadIdx.x;   // 8192 threads
    hbuf[i] = (__bf16)h0[i];
    unsigned short* hs = (unsigned short*)hbuf;
    hs[B_ * H_ + i]     = 0x7FC0;             // poison buffer 1
    hs[2 * B_ * H_ + i] = 0x7FC0;             // poison buffer 2
    if (i < G4) {
        int w = i >> 5, n = i & 31;
        int row = (n >> 3) * 512 + w * JJ + (n & 7);
        biasp[i] = bi[row] + bh[row];
    }
}

// ---- persistent recurrent kernel ----
__global__ __launch_bounds__(256) void lstm_main(
    const float* __restrict__ c0,
    const __bf16* __restrict__ xp,
    const __bf16* __restrict__ wip,
    const __bf16* __restrict__ whp,
    const float* __restrict__ biasp,
    __bf16* hbuf,                 // [3][B_][H_], buffers 1,2 pre-poisoned
    float* __restrict__ out)
{
    const int w    = blockIdx.x;
    const int tid  = threadIdx.x;
    const int wave = tid >> 6;
    const int lane = tid & 63;
    const int quad = lane >> 4;
    const int n16  = lane & 15;

    __shared__ float red[2][8][256];    // double-buffered by t&1 (distance-2 safety)
    __shared__ float hstage[16][9];     // padded: no bank conflicts

    // persistent weight fragments in VGPRs: this wave covers k in [wave*128, wave*128+128)
    const int kbase = wave * 128;
    bf16x8 bwx[2][4], bwh[2][4];
#pragma unroll
    for (int tile = 0; tile < 2; ++tile)
#pragma unroll
        for (int kc = 0; kc < 4; ++kc) {
            int k0 = kbase + kc * 32 + quad * 8;
            size_t idx = ((size_t)(w * 32 + tile * 16 + n16)) * 512 + k0;
            bwx[tile][kc] = *(const bf16x8*)(wip + idx);
            bwh[tile][kc] = *(const bf16x8*)(whp + idx);
        }

    // epilogue split: wave v owns acc reg index v => batches m = quad*4 + v
    const int col = w * JJ + (n16 & 7);
    const int mQ  = quad * 4 + wave;
    float creg = c0[(size_t)mQ * H_ + col];          // meaningful on lanes n16<8
    const float bias0 = biasp[w * 32 + n16];
    const float bias1 = biasp[w * 32 + 16 + n16];

    float* outHT = out + (size_t)B_ * T_ * H_;
    float* outCT = outHT + (size_t)B_ * H_;

    // ---- x-side pipeline prologue: accx = x-partial for t=0; axr = ax data for t=1
    bf16x8 axr[4], axrN[4];
    f32x4 accx0 = {0.f, 0.f, 0.f, 0.f}, accx1 = {0.f, 0.f, 0.f, 0.f};
#pragma unroll
    for (int kc = 0; kc < 4; ++kc) {
        int k0 = kbase + kc * 32 + quad * 8;
        axr[kc] = *(const bf16x8*)(xp + ((size_t)(0 * B_ + n16)) * I_ + k0);
    }
#pragma unroll
    for (int kc = 0; kc < 4; ++kc) {
        accx0 = __builtin_amdgcn_mfma_f32_16x16x32_bf16(axr[kc], bwx[0][kc], accx0, 0, 0, 0);
        accx1 = __builtin_amdgcn_mfma_f32_16x16x32_bf16(axr[kc], bwx[1][kc], accx1, 0, 0, 0);
    }
#pragma unroll
    for (int kc = 0; kc < 4; ++kc) {
        int k0 = kbase + kc * 32 + quad * 8;
        axr[kc] = *(const bf16x8*)(xp + ((size_t)(1 * B_ + n16)) * I_ + k0);
    }

    int bR = 0, bW = 1, bP = 2;   // read(t%3) / write((t+1)%3) / poison((t+2)%3)

    for (int t = 0; t < T_; ++t) {
        // ---- ONE CHANGE vs R14: software-pipelined ping-pong poll. Two load
        // batches in flight; checking batch A only waits for A's (older) loads —
        // the compiler's counted vmcnt leaves batch B outstanding. Catch latency
        // drops from ~1 poll RT to ~RT/2. Sentinel validity is monotonic, so
        // accepting the older batch is safe.
        const unsigned long long* hr64 =
            (const unsigned long long*)(hbuf + (size_t)bR * (B_ * H_));
        const size_t hb64 = (size_t)n16 * 128 + (kbase >> 2) + quad * 2;
        union U16 { unsigned long long u[2]; bf16x8 v; };
        U16 ah[4], pa[4], pb[4];
#pragma unroll
        for (int kc = 0; kc < 4; ++kc) {
            pa[kc].u[0] = __hip_atomic_load(hr64 + hb64 + kc * 8,
                                            __ATOMIC_RELAXED, __HIP_MEMORY_SCOPE_AGENT);
            pa[kc].u[1] = __hip_atomic_load(hr64 + hb64 + kc * 8 + 1,
                                            __ATOMIC_RELAXED, __HIP_MEMORY_SCOPE_AGENT);
        }
        for (;;) {
            // issue B before touching A's values
#pragma unroll
            for (int kc = 0; kc < 4; ++kc) {
                pb[kc].u[0] = __hip_atomic_load(hr64 + hb64 + kc * 8,
                                                __ATOMIC_RELAXED, __HIP_MEMORY_SCOPE_AGENT);
                pb[kc].u[1] = __hip_atomic_load(hr64 + hb64 + kc * 8 + 1,
                                                __ATOMIC_RELAXED, __HIP_MEMORY_SCOPE_AGENT);
            }
            bool okA = true;
#pragma unroll
            for (int kc = 0; kc < 4; ++kc)
                okA = okA && (pa[kc].u[0] != SENT64) && (pa[kc].u[1] != SENT64);
            if (__all((int)okA)) {
#pragma unroll
                for (int kc = 0; kc < 4; ++kc) ah[kc] = pa[kc];
                break;
            }
            // reissue A before touching B's values
#pragma unroll
            for (int kc = 0; kc < 4; ++kc) {
                pa[kc].u[0] = __hip_atomic_load(hr64 + hb64 + kc * 8,
                                                __ATOMIC_RELAXED, __HIP_MEMORY_SCOPE_AGENT);
                pa[kc].u[1] = __hip_atomic_load(hr64 + hb64 + kc * 8 + 1,
                                                __ATOMIC_RELAXED, __HIP_MEMORY_SCOPE_AGENT);
            }
            bool okB = true;
#pragma unroll
            for (int kc = 0; kc < 4; ++kc)
                okB = okB && (pb[kc].u[0] != SENT64) && (pb[kc].u[1] != SENT64);
            if (__all((int)okB)) {
#pragma unroll
                for (int kc = 0; kc < 4; ++kc) ah[kc] = pb[kc];
                break;
            }
        }

        // xp prefetch for t+2 (post-poll, R14): whole step to land before use
        if (t + 2 < T_) {
#pragma unroll
            for (int kc = 0; kc < 4; ++kc) {
                int k0 = kbase + kc * 32 + quad * 8;
                axrN[kc] = *(const bf16x8*)(xp + ((size_t)((t + 2) * B_ + n16)) * I_ + k0);
            }
        }

        // h-side GEMM, seeded from the pre-computed x-partials
        f32x4 acc0 = accx0, acc1 = accx1;
#pragma unroll
        for (int kc = 0; kc < 4; ++kc) {
            acc0 = __builtin_amdgcn_mfma_f32_16x16x32_bf16(ah[kc].v, bwh[0][kc], acc0, 0, 0, 0);
            acc1 = __builtin_amdgcn_mfma_f32_16x16x32_bf16(ah[kc].v, bwh[1][kc], acc1, 0, 0, 0);
        }

        // cross-wave K reduction through LDS (double-buffered)
#pragma unroll
        for (int r = 0; r < 4; ++r) {
            red[t & 1][r][tid]     = acc0[r];
            red[t & 1][4 + r][tid] = acc1[r];
        }
        __syncthreads();
        // syncthreads passed => all 4 waves' polls passed => ALL 64 chunks of h(t)
        // arrived => every WG is past its (t-1) h-read of buffer bP => safe to poison.

        // poison own rows of buffer bP early. Same-lane same-address ordering vs the
        // next data store is guaranteed: every counted vmcnt wait retires all but
        // the newest few ops, and the poison is hundreds of ops older by then.
        if (t + 2 < T_ && lane < 4) {
            int m4 = lane * 4 + wave;
            unsigned long long* pp =
                (unsigned long long*)(hbuf + (size_t)bP * (B_ * H_)) +
                (((size_t)m4 * H_ + w * JJ) >> 2);
            __hip_atomic_store(pp,     SENT64, __ATOMIC_RELAXED, __HIP_MEMORY_SCOPE_AGENT);
            __hip_atomic_store(pp + 1, SENT64, __ATOMIC_RELAXED, __HIP_MEMORY_SCOPE_AGENT);
        }

        // ---- distributed epilogue: wave v handles batches m = quad*4 + v
        float g80 = red[t & 1][wave][lane]       + red[t & 1][wave][64 + lane] +
                    red[t & 1][wave][128 + lane] + red[t & 1][wave][192 + lane];
        float g81 = red[t & 1][4 + wave][lane]       + red[t & 1][4 + wave][64 + lane] +
                    red[t & 1][4 + wave][128 + lane] + red[t & 1][4 + wave][192 + lane];

        float v0 = g80 + bias0;   // tile0: i (n16<8) | f (n16>=8)
        float v1 = g81 + bias1;   // tile1: g (n16<8) | o (n16>=8)
        float p0 = __shfl_xor(v0, 8, 64);
        float p1 = __shfl_xor(v1, 8, 64);
        if (n16 < 8) {
            float ig = sigm(v0), fg = sigm(p0), gg = tanh_f(v1), og = sigm(p1);
            float c = fg * creg + ig * gg;
            creg = c;
            float h = og * tanh_f(c);
            hstage[mQ][n16] = h;
            if (t == T_ - 1) {
                outHT[(size_t)mQ * H_ + col] = h;
                outCT[(size_t)mQ * H_ + col] = c;
            }
        }
        // wave-internal LDS write->read ordering (ds ops retire in order per wave)
        asm volatile("s_waitcnt lgkmcnt(0)" ::: "memory");

        if (lane < 4) {
            int m4 = lane * 4 + wave;
            float hv[8];
#pragma unroll
            for (int j = 0; j < 8; ++j) hv[j] = hstage[m4][j];
            if (t < T_ - 1) {
                bf16x4 lo = {(__bf16)hv[0], (__bf16)hv[1], (__bf16)hv[2], (__bf16)hv[3]};
                bf16x4 hi = {(__bf16)hv[4], (__bf16)hv[5], (__bf16)hv[6], (__bf16)hv[7]};
                unsigned long long* hw64 =
                    (unsigned long long*)(hbuf + (size_t)bW * (B_ * H_)) +
                    (((size_t)m4 * H_ + w * JJ) >> 2);
                // plain relaxed agent stores: readers self-validate, no drain/flag
                __hip_atomic_store(hw64,     __builtin_bit_cast(unsigned long long, lo),
                                   __ATOMIC_RELAXED, __HIP_MEMORY_SCOPE_AGENT);
                __hip_atomic_store(hw64 + 1, __builtin_bit_cast(unsigned long long, hi),
                                   __ATOMIC_RELAXED, __HIP_MEMORY_SCOPE_AGENT);
            }
            // fp32 out stores — off the inter-WG critical path
            float* op = out + ((size_t)m4 * T_ + t) * H_ + w * JJ;
            *(f32x4*)op       = (f32x4){hv[0], hv[1], hv[2], hv[3]};
            *((f32x4*)op + 1) = (f32x4){hv[4], hv[5], hv[6], hv[7]};
        }

        if (t == T_ - 1) break;

        // ---- x-side GEMM for t+1 in the wait shadow (register-only)
        {
            f32x4 nx0 = {0.f, 0.f, 0.f, 0.f}, nx1 = {0.f, 0.f, 0.f, 0.f};
#pragma unroll
            for (int kc = 0; kc < 4; ++kc) {
                nx0 = __builtin_amdgcn_mfma_f32_16x16x32_bf16(axr[kc], bwx[0][kc], nx0, 0, 0, 0);
                nx1 = __builtin_amdgcn_mfma_f32_16x16x32_bf16(axr[kc], bwx[1][kc], nx1, 0, 0, 0);
            }
            accx0 = nx0; accx1 = nx1;
            if (t + 2 < T_) {
#pragma unroll
                for (int kc = 0; kc < 4; ++kc) axr[kc] = axrN[kc];   // static copy
            }
        }

        int tmp = bR; bR = bW; bW = bP; bP = tmp;   // rotate 3 buffers
    }
}

extern "C" void kernel_launch(void* const* d_in, const int* in_sizes, int n_in,
                              void* d_out, int out_size, void* d_ws, size_t ws_size,
                              hipStream_t stream) {
    const float* x  = (const float*)d_in[0];
    const float* h0 = (const float*)d_in[1];
    const float* c0 = (const float*)d_in[2];
    const float* Wi = (const float*)d_in[3];
    const float* bi = (const float*)d_in[4];
    const float* Wh = (const float*)d_in[5];
    const float* bh = (const float*)d_in[6];
    float* out = (float*)d_out;

    char* ws = (char*)d_ws;
    __bf16*   xp    = (__bf16*)ws;                         // 32 MB
    __bf16*   wip   = (__bf16*)(ws + 33554432);            // 2 MB
    __bf16*   whp   = (__bf16*)(ws + 35651584);            // 2 MB
    float*    biasp = (float*) (ws + 37748736);            // 8 KB
    __bf16*   hbuf  = (__bf16*)(ws + 37756928);            // 3 x 16 KB

    pack_x<<<16384, 256, 0, stream>>>(x, xp);
    pack_w<<<2048, 256, 0, stream>>>(Wi, Wh, wip, whp);
    prep_small<<<32, 256, 0, stream>>>(h0, bi, bh, hbuf, biasp);

    void* args[] = { (void*)&c0, (void*)&xp, (void*)&wip, (void*)&whp, (void*)&biasp,
                     (void*)&hbuf, (void*)&out };
    hipLaunchCooperativeKernel((void*)lstm_main, dim3(NW), dim3(256), args, 0, stream);
}

// Round 18
// 6200.169 us; speedup vs baseline: 1.3494x; 1.3494x over previous
//
#include <hip/hip_runtime.h>
#include <stdint.h>

#define B_ 16
#define T_ 2048
#define I_ 512
#define H_ 512
#define G4 2048
#define NW 64          // workgroups in the persistent kernel
#define JJ 8           // h-columns owned per WG (H_/NW)

// bf16 NaN sentinel: |h| < 1 always (h = sigm*tanh), h0 is finite normal data,
// so 0x7FC0 can never occur in live h data.
#define SENT64 0x7FC07FC07FC07FC0ULL

typedef __bf16 bf16x8 __attribute__((ext_vector_type(8)));
typedef __bf16 bf16x4 __attribute__((ext_vector_type(4)));
typedef float  f32x4  __attribute__((ext_vector_type(4)));

__device__ __forceinline__ float sigm(float x) {
    return __builtin_amdgcn_rcpf(1.f + __builtin_amdgcn_exp2f(-1.44269504f * x));
}
__device__ __forceinline__ float tanh_f(float x) {
    float xc = fmaxf(x, -40.f);                       // avoid inf*0 = NaN
    float e  = __builtin_amdgcn_exp2f(-2.88539008f * xc);
    return (1.f - e) * __builtin_amdgcn_rcpf(1.f + e);
}

// ---- prep: x [B][T][I] fp32 -> xp [T][B][I] bf16 ----
__global__ void pack_x(const float* __restrict__ x, __bf16* __restrict__ xp) {
    int q = blockIdx.x * 256 + threadIdx.x;   // 4 elems each
    int o = q * 4;                            // dst linear over [T][B][I]
    int i  = o & (I_ - 1);
    int tb = o >> 9;
    int b  = tb & (B_ - 1);
    int t  = tb >> 4;
    float4 v = *(const float4*)(x + ((size_t)(b * T_ + t) * I_ + i));
    *(bf16x4*)(xp + o) = (bf16x4){(__bf16)v.x, (__bf16)v.y, (__bf16)v.z, (__bf16)v.w};
}

// ---- prep: pack Wi/Wh rows per-WG: wp[w][n][k], n = gate*8 + jj, row = gate*512 + w*8 + jj
__global__ void pack_w(const float* __restrict__ Wi, const float* __restrict__ Wh,
                       __bf16* __restrict__ wip, __bf16* __restrict__ whp) {
    int q = blockIdx.x * 256 + threadIdx.x;   // total 2*64*32*128 threads, 4 k each
    int k = (q & 127) * 4;  q >>= 7;
    int n = q & 31;         q >>= 5;
    int w = q & 63;         q >>= 6;
    int mat = q;
    int row = (n >> 3) * 512 + w * JJ + (n & 7);
    const float* src = (mat ? Wh : Wi) + (size_t)row * 512 + k;
    float4 v = *(const float4*)src;
    __bf16* dst = (mat ? whp : wip) + ((size_t)(w * 32 + n) * 512 + k);
    *(bf16x4*)dst = (bf16x4){(__bf16)v.x, (__bf16)v.y, (__bf16)v.z, (__bf16)v.w};
}

// ---- prep: h0 -> hbuf[0] (bf16), poison hbuf[1],hbuf[2], bias pack ----
__global__ void prep_small(const float* __restrict__ h0, const float* __restrict__ bi,
                           const float* __restrict__ bh, __bf16* __restrict__ hbuf,
                           float* __restrict__ biasp) {
    int i = blockIdx.x * 256 + threadIdx.x;   // 8192 threads
    hbuf[i] = (__bf16)h0[i];
    unsigned short* hs = (unsigned short*)hbuf;
    hs[B_ * H_ + i]     = 0x7FC0;             // poison buffer 1
    hs[2 * B_ * H_ + i] = 0x7FC0;             // poison buffer 2
    if (i < G4) {
        int w = i >> 5, n = i & 31;
        int row = (n >> 3) * 512 + w * JJ + (n & 7);
        biasp[i] = bi[row] + bh[row];
    }
}

// ---- persistent recurrent kernel ----
__global__ __launch_bounds__(256) void lstm_main(
    const float* __restrict__ c0,
    const __bf16* __restrict__ xp,
    const __bf16* __restrict__ wip,
    const __bf16* __restrict__ whp,
    const float* __restrict__ biasp,
    __bf16* hbuf,                 // [3][B_][H_], buffers 1,2 pre-poisoned
    float* __restrict__ out)
{
    const int w    = blockIdx.x;
    const int tid  = threadIdx.x;
    const int wave = tid >> 6;
    const int lane = tid & 63;
    const int quad = lane >> 4;
    const int n16  = lane & 15;

    __shared__ float red[2][8][256];    // double-buffered by t&1 (distance-2 safety)
    __shared__ float hstage[16][9];     // padded: no bank conflicts

    // persistent weight fragments in VGPRs: this wave covers k in [wave*128, wave*128+128)
    const int kbase = wave * 128;
    bf16x8 bwx[2][4], bwh[2][4];
#pragma unroll
    for (int tile = 0; tile < 2; ++tile)
#pragma unroll
        for (int kc = 0; kc < 4; ++kc) {
            int k0 = kbase + kc * 32 + quad * 8;
            size_t idx = ((size_t)(w * 32 + tile * 16 + n16)) * 512 + k0;
            bwx[tile][kc] = *(const bf16x8*)(wip + idx);
            bwh[tile][kc] = *(const bf16x8*)(whp + idx);
        }

    // epilogue split: wave v owns acc reg index v => batches m = quad*4 + v
    const int col = w * JJ + (n16 & 7);
    const int mQ  = quad * 4 + wave;
    float creg = c0[(size_t)mQ * H_ + col];          // meaningful on lanes n16<8
    const float bias0 = biasp[w * 32 + n16];
    const float bias1 = biasp[w * 32 + 16 + n16];

    float* outHT = out + (size_t)B_ * T_ * H_;
    float* outCT = outHT + (size_t)B_ * H_;

    // ---- x-side pipeline prologue: accx = x-partial for t=0; axr = ax data for t=1
    bf16x8 axr[4], axrN[4];
    f32x4 accx0 = {0.f, 0.f, 0.f, 0.f}, accx1 = {0.f, 0.f, 0.f, 0.f};
#pragma unroll
    for (int kc = 0; kc < 4; ++kc) {
        int k0 = kbase + kc * 32 + quad * 8;
        axr[kc] = *(const bf16x8*)(xp + ((size_t)(0 * B_ + n16)) * I_ + k0);
    }
#pragma unroll
    for (int kc = 0; kc < 4; ++kc) {
        accx0 = __builtin_amdgcn_mfma_f32_16x16x32_bf16(axr[kc], bwx[0][kc], accx0, 0, 0, 0);
        accx1 = __builtin_amdgcn_mfma_f32_16x16x32_bf16(axr[kc], bwx[1][kc], accx1, 0, 0, 0);
    }
#pragma unroll
    for (int kc = 0; kc < 4; ++kc) {
        int k0 = kbase + kc * 32 + quad * 8;
        axr[kc] = *(const bf16x8*)(xp + ((size_t)(1 * B_ + n16)) * I_ + k0);
    }

    int bR = 0, bW = 1, bP = 2;   // read(t%3) / write((t+1)%3) / poison((t+2)%3)

    for (int t = 0; t < T_; ++t) {
        // ---- combined poll+load: data is self-validating (sentinel protocol).
        // ONE CHANGE vs R14: retries reload ONLY still-poison chunks (per-lane
        // predicated, exec-masked). Chunk validity is monotonic and FINAL (each
        // chunk written once), so cached valid chunks are safe to keep. This cuts
        // retry traffic ~4-8x — R17 measured the poll path is LLC-congestion-
        // sensitive (doubling poll loads cost +0.85us/step).
        const unsigned long long* hr64 =
            (const unsigned long long*)(hbuf + (size_t)bR * (B_ * H_));
        const size_t hb64 = (size_t)n16 * 128 + (kbase >> 2) + quad * 2;
        union { unsigned long long u[2]; bf16x8 v; } ah[4];
        bool okc[4];
#pragma unroll
        for (int kc = 0; kc < 4; ++kc) {
            ah[kc].u[0] = __hip_atomic_load(hr64 + hb64 + kc * 8,
                                            __ATOMIC_RELAXED, __HIP_MEMORY_SCOPE_AGENT);
            ah[kc].u[1] = __hip_atomic_load(hr64 + hb64 + kc * 8 + 1,
                                            __ATOMIC_RELAXED, __HIP_MEMORY_SCOPE_AGENT);
        }
#pragma unroll
        for (int kc = 0; kc < 4; ++kc)
            okc[kc] = (ah[kc].u[0] != SENT64) & (ah[kc].u[1] != SENT64);
        for (;;) {
            bool all4 = okc[0] & okc[1] & okc[2] & okc[3];
            if (__all((int)all4)) break;
            __builtin_amdgcn_s_sleep(1);
#pragma unroll
            for (int kc = 0; kc < 4; ++kc) {
                if (!okc[kc]) {
                    ah[kc].u[0] = __hip_atomic_load(hr64 + hb64 + kc * 8,
                                                    __ATOMIC_RELAXED, __HIP_MEMORY_SCOPE_AGENT);
                    ah[kc].u[1] = __hip_atomic_load(hr64 + hb64 + kc * 8 + 1,
                                                    __ATOMIC_RELAXED, __HIP_MEMORY_SCOPE_AGENT);
                    okc[kc] = (ah[kc].u[0] != SENT64) & (ah[kc].u[1] != SENT64);
                }
            }
        }

        // xp prefetch for t+2 (post-poll, R14): whole step to land before use
        if (t + 2 < T_) {
#pragma unroll
            for (int kc = 0; kc < 4; ++kc) {
                int k0 = kbase + kc * 32 + quad * 8;
                axrN[kc] = *(const bf16x8*)(xp + ((size_t)((t + 2) * B_ + n16)) * I_ + k0);
            }
        }

        // h-side GEMM, seeded from the pre-computed x-partials
        f32x4 acc0 = accx0, acc1 = accx1;
#pragma unroll
        for (int kc = 0; kc < 4; ++kc) {
            acc0 = __builtin_amdgcn_mfma_f32_16x16x32_bf16(ah[kc].v, bwh[0][kc], acc0, 0, 0, 0);
            acc1 = __builtin_amdgcn_mfma_f32_16x16x32_bf16(ah[kc].v, bwh[1][kc], acc1, 0, 0, 0);
        }

        // cross-wave K reduction through LDS (double-buffered)
#pragma unroll
        for (int r = 0; r < 4; ++r) {
            red[t & 1][r][tid]     = acc0[r];
            red[t & 1][4 + r][tid] = acc1[r];
        }
        __syncthreads();
        // syncthreads passed => all 4 waves' polls passed => ALL 64 chunks of h(t)
        // arrived => every WG is past its (t-1) h-read of buffer bP => safe to poison.

        // poison own rows of buffer bP early; acked before next data store via the
        // in-order vmcnt drains inside next step's poll.
        if (t + 2 < T_ && lane < 4) {
            int m4 = lane * 4 + wave;
            unsigned long long* pp =
                (unsigned long long*)(hbuf + (size_t)bP * (B_ * H_)) +
                (((size_t)m4 * H_ + w * JJ) >> 2);
            __hip_atomic_store(pp,     SENT64, __ATOMIC_RELAXED, __HIP_MEMORY_SCOPE_AGENT);
            __hip_atomic_store(pp + 1, SENT64, __ATOMIC_RELAXED, __HIP_MEMORY_SCOPE_AGENT);
        }

        // ---- distributed epilogue: wave v handles batches m = quad*4 + v
        float g80 = red[t & 1][wave][lane]       + red[t & 1][wave][64 + lane] +
                    red[t & 1][wave][128 + lane] + red[t & 1][wave][192 + lane];
        float g81 = red[t & 1][4 + wave][lane]       + red[t & 1][4 + wave][64 + lane] +
                    red[t & 1][4 + wave][128 + lane] + red[t & 1][4 + wave][192 + lane];

        float v0 = g80 + bias0;   // tile0: i (n16<8) | f (n16>=8)
        float v1 = g81 + bias1;   // tile1: g (n16<8) | o (n16>=8)
        float p0 = __shfl_xor(v0, 8, 64);
        float p1 = __shfl_xor(v1, 8, 64);
        if (n16 < 8) {
            float ig = sigm(v0), fg = sigm(p0), gg = tanh_f(v1), og = sigm(p1);
            float c = fg * creg + ig * gg;
            creg = c;
            float h = og * tanh_f(c);
            hstage[mQ][n16] = h;
            if (t == T_ - 1) {
                outHT[(size_t)mQ * H_ + col] = h;
                outCT[(size_t)mQ * H_ + col] = c;
            }
        }
        // wave-internal LDS write->read ordering (ds ops retire in order per wave)
        asm volatile("s_waitcnt lgkmcnt(0)" ::: "memory");

        if (lane < 4) {
            int m4 = lane * 4 + wave;
            float hv[8];
#pragma unroll
            for (int j = 0; j < 8; ++j) hv[j] = hstage[m4][j];
            if (t < T_ - 1) {
                bf16x4 lo = {(__bf16)hv[0], (__bf16)hv[1], (__bf16)hv[2], (__bf16)hv[3]};
                bf16x4 hi = {(__bf16)hv[4], (__bf16)hv[5], (__bf16)hv[6], (__bf16)hv[7]};
                unsigned long long* hw64 =
                    (unsigned long long*)(hbuf + (size_t)bW * (B_ * H_)) +
                    (((size_t)m4 * H_ + w * JJ) >> 2);
                // plain relaxed agent stores: readers self-validate, no drain/flag
                __hip_atomic_store(hw64,     __builtin_bit_cast(unsigned long long, lo),
                                   __ATOMIC_RELAXED, __HIP_MEMORY_SCOPE_AGENT);
                __hip_atomic_store(hw64 + 1, __builtin_bit_cast(unsigned long long, hi),
                                   __ATOMIC_RELAXED, __HIP_MEMORY_SCOPE_AGENT);
            }
            // fp32 out stores — off the inter-WG critical path
            float* op = out + ((size_t)m4 * T_ + t) * H_ + w * JJ;
            *(f32x4*)op       = (f32x4){hv[0], hv[1], hv[2], hv[3]};
            *((f32x4*)op + 1) = (f32x4){hv[4], hv[5], hv[6], hv[7]};
        }

        if (t == T_ - 1) break;

        // ---- x-side GEMM for t+1 in the wait shadow (register-only)
        {
            f32x4 nx0 = {0.f, 0.f, 0.f, 0.f}, nx1 = {0.f, 0.f, 0.f, 0.f};
#pragma unroll
            for (int kc = 0; kc < 4; ++kc) {
                nx0 = __builtin_amdgcn_mfma_f32_16x16x32_bf16(axr[kc], bwx[0][kc], nx0, 0, 0, 0);
                nx1 = __builtin_amdgcn_mfma_f32_16x16x32_bf16(axr[kc], bwx[1][kc], nx1, 0, 0, 0);
            }
            accx0 = nx0; accx1 = nx1;
            if (t + 2 < T_) {
#pragma unroll
                for (int kc = 0; kc < 4; ++kc) axr[kc] = axrN[kc];   // static copy
            }
        }

        int tmp = bR; bR = bW; bW = bP; bP = tmp;   // rotate 3 buffers
    }
}

extern "C" void kernel_launch(void* const* d_in, const int* in_sizes, int n_in,
                              void* d_out, int out_size, void* d_ws, size_t ws_size,
                              hipStream_t stream) {
    const float* x  = (const float*)d_in[0];
    const float* h0 = (const float*)d_in[1];
    const float* c0 = (const float*)d_in[2];
    const float* Wi = (const float*)d_in[3];
    const float* bi = (const float*)d_in[4];
    const float* Wh = (const float*)d_in[5];
    const float* bh = (const float*)d_in[6];
    float* out = (float*)d_out;

    char* ws = (char*)d_ws;
    __bf16*   xp    = (__bf16*)ws;                         // 32 MB
    __bf16*   wip   = (__bf16*)(ws + 33554432);            // 2 MB
    __bf16*   whp   = (__bf16*)(ws + 35651584);            // 2 MB
    float*    biasp = (float*) (ws + 37748736);            // 8 KB
    __bf16*   hbuf  = (__bf16*)(ws + 37756928);            // 3 x 16 KB

    pack_x<<<16384, 256, 0, stream>>>(x, xp);
    pack_w<<<2048, 256, 0, stream>>>(Wi, Wh, wip, whp);
    prep_small<<<32, 256, 0, stream>>>(h0, bi, bh, hbuf, biasp);

    void* args[] = { (void*)&c0, (void*)&xp, (void*)&wip, (void*)&whp, (void*)&biasp,
                     (void*)&hbuf, (void*)&out };
    hipLaunchCooperativeKernel((void*)lstm_main, dim3(NW), dim3(256), args, 0, stream);
}